// Round 4
// baseline (159.895 us; speedup 1.0000x reference)
//
#include <hip/hip_runtime.h>

// Problem constants
#define BB 2
#define LL 2048
#define DD 2048
#define NS 16      // d_state
#define RK 64      // dt_rank
#define NP 96      // RK + 2*NS
#define NC 32      // chunks
#define CT 64      // L / NC
#define KSPLIT 8
#define LOG2E 1.4426950408889634f

#define EXP2F(v) __builtin_amdgcn_exp2f(v)

#define FMA4(acc, a, b)                  \
    acc = fmaf((a).x, (b).x, acc);       \
    acc = fmaf((a).y, (b).y, acc);       \
    acc = fmaf((a).z, (b).z, acc);       \
    acc = fmaf((a).w, (b).w, acc);

// ---------------------------------------------------------------------------
// K1: partial xp for one K-slice.  part[ks][r][p] = sum_{k in slice} x[r][k]*Wx[p][k]
// grid (64 row-blocks, 8 k-slices) x 256 threads. Tile 64 rows x 96 cols, BK=64.
// acc[4][6] per thread: 96 FMA4 per 10 LDS b128 reads (a-reads are 16-lane
// broadcast). LDS 43.5 KB -> 2 blocks/CU.
// ---------------------------------------------------------------------------
__global__ __launch_bounds__(256, 2) void k_proj1(const float* __restrict__ x,
                                                  const float* __restrict__ Wx,
                                                  float* __restrict__ part) {
    __shared__ float xs[64][68];
    __shared__ float wts[96][68];
    const int tid = threadIdx.x;
    const int r0 = blockIdx.x * 64;
    const int kbase = blockIdx.y * (DD / KSPLIT);   // 256-wide K slice
    const int rq = tid >> 4;   // 0..15 -> rows rq + 16*i, i=0..3
    const int cq = tid & 15;   // 0..15 -> cols cq + 16*j, j=0..5
    float acc[4][6];
    #pragma unroll
    for (int i = 0; i < 4; ++i)
        #pragma unroll
        for (int j = 0; j < 6; ++j) acc[i][j] = 0.f;

    for (int k0 = kbase; k0 < kbase + DD / KSPLIT; k0 += 64) {
        #pragma unroll
        for (int i = 0; i < 4; ++i) {
            int idx = tid + i*256;          // 64 rows x 16 float4
            int row = idx >> 4, v = idx & 15;
            *(float4*)&xs[row][v*4] =
                *(const float4*)&x[(size_t)(r0+row)*DD + k0 + v*4];
        }
        #pragma unroll
        for (int i = 0; i < 6; ++i) {
            int idx = tid + i*256;          // 96 rows x 16 float4
            int row = idx >> 4, v = idx & 15;
            *(float4*)&wts[row][v*4] =
                *(const float4*)&Wx[(size_t)row*DD + k0 + v*4];
        }
        __syncthreads();
        #pragma unroll
        for (int k4 = 0; k4 < 16; ++k4) {
            float4 av[4];
            #pragma unroll
            for (int i = 0; i < 4; ++i) av[i] = *(const float4*)&xs[rq+16*i][k4*4];
            #pragma unroll
            for (int j = 0; j < 6; ++j) {
                float4 b = *(const float4*)&wts[cq+16*j][k4*4];
                #pragma unroll
                for (int i = 0; i < 4; ++i) {
                    FMA4(acc[i][j], av[i], b);
                }
            }
        }
        __syncthreads();
    }
    float* pout = part + (size_t)blockIdx.y * 4096 * NP;
    #pragma unroll
    for (int i = 0; i < 4; ++i)
        #pragma unroll
        for (int j = 0; j < 6; ++j)
            pout[(size_t)(r0 + rq + 16*i)*NP + cq + 16*j] = acc[i][j];
}

// ---------------------------------------------------------------------------
// K1b: xp = sum over 8 K-slice partials. 98304 float4s.
// ---------------------------------------------------------------------------
__global__ __launch_bounds__(256) void k_reduce(const float* __restrict__ part,
                                                float* __restrict__ xp) {
    const int i = blockIdx.x*256 + threadIdx.x;   // float4 index, < 98304
    const float4* p = (const float4*)part;
    float4 s = p[i];
    #pragma unroll
    for (int ks = 1; ks < KSPLIT; ++ks) {
        float4 v = p[(size_t)ks*98304 + i];
        s.x += v.x; s.y += v.y; s.z += v.z; s.w += v.w;
    }
    ((float4*)xp)[i] = s;
}

// ---------------------------------------------------------------------------
// K2: delta[r][d] = softplus( sum_k xp[r][k] * Wdt[d][k] + bdt[d] ), k<64
// Wdt-in-registers: thread owns column d = d0 + tid (16 float4 of weights).
// delta_p rows staged in LDS, read wave-uniform (broadcast, ~free).
// EVERY thread iterates ALL 64 rows of the tile (fixes R3 undercoverage).
// grid (64 row-blocks, 8 col-blocks) x 256 threads; 64 rows x 256 cols/block.
// ---------------------------------------------------------------------------
__global__ __launch_bounds__(256, 2) void k_proj2(const float* __restrict__ xp,
                                                  const float* __restrict__ Wdt,
                                                  const float* __restrict__ bdt,
                                                  float* __restrict__ delta) {
    __shared__ float dps[64][64];    // 16 KB; broadcast reads -> no pad needed
    const int tid = threadIdx.x;
    const int r0 = blockIdx.x * 64;
    const int d0 = blockIdx.y * 256;
    const int d  = d0 + tid;

    // own weights: Wdt[d][0..63]
    float4 w[16];
    {
        const float4* Wr = (const float4*)&Wdt[(size_t)d*RK];
        #pragma unroll
        for (int q = 0; q < 16; ++q) w[q] = Wr[q];
    }
    const float bd = bdt[d];

    // stage delta_p tile: 64 rows x 64 cols (= xp[:, :64])
    #pragma unroll
    for (int i = 0; i < 4; ++i) {
        int idx = tid + i*256;              // 64 rows x 16 float4
        int row = idx >> 4, v = idx & 15;
        *(float4*)&dps[row][v*4] =
            *(const float4*)&xp[(size_t)(r0+row)*NP + v*4];
    }
    __syncthreads();

    // all threads walk all 64 rows (2 per iteration, 4 indep accum chains each)
    #pragma unroll 2
    for (int rr = 0; rr < 32; ++rr) {
        const int rowA = rr*2;
        const int rowB = rowA + 1;
        float a0=0.f, a1=0.f, a2=0.f, a3=0.f;
        float b0=0.f, b1=0.f, b2=0.f, b3=0.f;
        #pragma unroll
        for (int q = 0; q < 16; q += 4) {
            float4 va0 = *(const float4*)&dps[rowA][(q+0)*4];
            float4 va1 = *(const float4*)&dps[rowA][(q+1)*4];
            float4 va2 = *(const float4*)&dps[rowA][(q+2)*4];
            float4 va3 = *(const float4*)&dps[rowA][(q+3)*4];
            FMA4(a0, va0, w[q+0]); FMA4(a1, va1, w[q+1]);
            FMA4(a2, va2, w[q+2]); FMA4(a3, va3, w[q+3]);
            float4 vb0 = *(const float4*)&dps[rowB][(q+0)*4];
            float4 vb1 = *(const float4*)&dps[rowB][(q+1)*4];
            float4 vb2 = *(const float4*)&dps[rowB][(q+2)*4];
            float4 vb3 = *(const float4*)&dps[rowB][(q+3)*4];
            FMA4(b0, vb0, w[q+0]); FMA4(b1, vb1, w[q+1]);
            FMA4(b2, vb2, w[q+2]); FMA4(b3, vb3, w[q+3]);
        }
        float zA = (a0+a1) + (a2+a3) + bd;
        float zB = (b0+b1) + (b2+b3) + bd;
        float spA = (zA > 15.f) ? zA : __logf(1.f + __expf(zA));
        float spB = (zB > 15.f) ? zB : __logf(1.f + __expf(zB));
        delta[(size_t)(r0+rowA)*DD + d] = spA;   // lanes = consecutive d: coalesced
        delta[(size_t)(r0+rowB)*DD + d] = spB;
    }
}

// ---------------------------------------------------------------------------
// K3 (pass 1): per (b, chunk, d): run chunk scan from h=0, store final state
// S[b][c][n][d] and sumdelta[b][c][d].  grid 512 x 256 threads.
// ---------------------------------------------------------------------------
__global__ __launch_bounds__(256) void k_scan1(const float* __restrict__ x,
                                               const float* __restrict__ delta,
                                               const float* __restrict__ xp,
                                               const float* __restrict__ A_log,
                                               float* __restrict__ S,
                                               float* __restrict__ sumdelta) {
    const int bid = blockIdx.x;          // b*256 + c*8 + dq
    const int dq = bid & 7;
    const int c  = (bid >> 3) & (NC-1);
    const int b  = bid >> 8;
    const int d  = dq*256 + threadIdx.x;

    float A2[NS];
    {
        const float4* Ar = (const float4*)&A_log[(size_t)d*NS];
        #pragma unroll
        for (int q = 0; q < 4; ++q) {
            float4 v = Ar[q];
            A2[q*4+0] = -__expf(v.x) * LOG2E;
            A2[q*4+1] = -__expf(v.y) * LOG2E;
            A2[q*4+2] = -__expf(v.z) * LOG2E;
            A2[q*4+3] = -__expf(v.w) * LOG2E;
        }
    }
    float h[NS];
    #pragma unroll
    for (int n = 0; n < NS; ++n) h[n] = 0.f;
    float sd = 0.f;

    const int t0 = c * CT;
    size_t base = ((size_t)b*LL + t0)*DD + d;
    for (int t = t0; t < t0 + CT; ++t) {
        float dlt = delta[base];
        float xv  = x[base];
        sd += dlt;
        float dx = dlt * xv;
        const float4* Bp4 = (const float4*)&xp[((size_t)b*LL + t)*NP + RK];
        float bp[NS];
        *(float4*)&bp[0]  = Bp4[0];
        *(float4*)&bp[4]  = Bp4[1];
        *(float4*)&bp[8]  = Bp4[2];
        *(float4*)&bp[12] = Bp4[3];
        #pragma unroll
        for (int n = 0; n < NS; ++n)
            h[n] = EXP2F(A2[n]*dlt)*h[n] + dx*bp[n];
        base += DD;
    }
    size_t so = ((size_t)(b*NC + c)*NS)*DD + d;
    #pragma unroll
    for (int n = 0; n < NS; ++n) S[so + (size_t)n*DD] = h[n];
    sumdelta[((size_t)(b*NC + c))*DD + d] = sd;
}

// ---------------------------------------------------------------------------
// K4 (pass 2): cross-chunk recurrence, in place: S[c] <- state ENTERING chunk c.
// ---------------------------------------------------------------------------
__global__ __launch_bounds__(256) void k_scan2(const float* __restrict__ A_log,
                                               const float* __restrict__ sumdelta,
                                               float* __restrict__ S) {
    const int g = blockIdx.x*256 + threadIdx.x;   // (b*16+n)*2048 + d
    const int d = g & (DD-1);
    const int n = (g >> 11) & (NS-1);
    const int b = g >> 15;
    const float A2 = -__expf(A_log[(size_t)d*NS + n]) * LOG2E;
    float carry = 0.f;
    for (int c = 0; c < NC; ++c) {
        size_t si = ((size_t)(b*NC + c)*NS + n)*DD + d;
        float s  = S[si];
        float sd = sumdelta[((size_t)(b*NC + c))*DD + d];
        S[si] = carry;                       // state entering chunk c
        carry = EXP2F(A2*sd)*carry + s;      // state after chunk c
    }
}

// ---------------------------------------------------------------------------
// K5 (pass 3): replay each chunk from its true incoming state, emit y.
// ---------------------------------------------------------------------------
__global__ __launch_bounds__(256) void k_scan3(const float* __restrict__ x,
                                               const float* __restrict__ delta,
                                               const float* __restrict__ xp,
                                               const float* __restrict__ A_log,
                                               const float* __restrict__ Dv,
                                               const float* __restrict__ S,
                                               float* __restrict__ y) {
    const int bid = blockIdx.x;
    const int dq = bid & 7;
    const int c  = (bid >> 3) & (NC-1);
    const int b  = bid >> 8;
    const int d  = dq*256 + threadIdx.x;

    float A2[NS];
    {
        const float4* Ar = (const float4*)&A_log[(size_t)d*NS];
        #pragma unroll
        for (int q = 0; q < 4; ++q) {
            float4 v = Ar[q];
            A2[q*4+0] = -__expf(v.x) * LOG2E;
            A2[q*4+1] = -__expf(v.y) * LOG2E;
            A2[q*4+2] = -__expf(v.z) * LOG2E;
            A2[q*4+3] = -__expf(v.w) * LOG2E;
        }
    }
    float h[NS];
    size_t so = ((size_t)(b*NC + c)*NS)*DD + d;
    #pragma unroll
    for (int n = 0; n < NS; ++n) h[n] = S[so + (size_t)n*DD];
    const float Dd = Dv[d];

    const int t0 = c * CT;
    size_t base = ((size_t)b*LL + t0)*DD + d;
    for (int t = t0; t < t0 + CT; ++t) {
        float dlt = delta[base];
        float xv  = x[base];
        float dx = dlt * xv;
        const float4* Pr = (const float4*)&xp[((size_t)b*LL + t)*NP + RK];
        float bp[NS], cp[NS];
        *(float4*)&bp[0]  = Pr[0];
        *(float4*)&bp[4]  = Pr[1];
        *(float4*)&bp[8]  = Pr[2];
        *(float4*)&bp[12] = Pr[3];
        *(float4*)&cp[0]  = Pr[4];   // C_proj = xp[:, 80:96]
        *(float4*)&cp[4]  = Pr[5];
        *(float4*)&cp[8]  = Pr[6];
        *(float4*)&cp[12] = Pr[7];
        float yt = 0.f;
        #pragma unroll
        for (int n = 0; n < NS; ++n) {
            h[n] = EXP2F(A2[n]*dlt)*h[n] + dx*bp[n];
            yt += h[n]*cp[n];
        }
        y[base] = yt + xv*Dd;
        base += DD;
    }
}

// ---------------------------------------------------------------------------
extern "C" void kernel_launch(void* const* d_in, const int* in_sizes, int n_in,
                              void* d_out, int out_size, void* d_ws, size_t ws_size,
                              hipStream_t stream) {
    const float* x     = (const float*)d_in[0];
    const float* A_log = (const float*)d_in[1];
    const float* Dv    = (const float*)d_in[2];
    const float* Wx    = (const float*)d_in[3];
    const float* Wdt   = (const float*)d_in[4];
    const float* bdt   = (const float*)d_in[5];
    float* y = (float*)d_out;

    // ws layout (floats): xp[4096*96] | delta[4096*2048] | S[2*32*16*2048] | sumdelta[2*32*2048]
    // proj1 partials (8*4096*96 floats = 12.6 MB) live temporarily in the delta
    // region; delta itself is written only after k_reduce completes.
    float* ws    = (float*)d_ws;
    float* xp    = ws;
    float* delta = xp + (size_t)4096*NP;
    float* S     = delta + (size_t)4096*DD;
    float* sumd  = S + (size_t)BB*NC*NS*DD;
    float* part  = delta;

    k_proj1<<<dim3(64, KSPLIT), 256, 0, stream>>>(x, Wx, part);
    k_reduce<<<384, 256, 0, stream>>>(part, xp);
    k_proj2<<<dim3(64, 8), 256, 0, stream>>>(xp, Wdt, bdt, delta);
    k_scan1<<<512, 256, 0, stream>>>(x, delta, xp, A_log, S, sumd);
    k_scan2<<<256, 256, 0, stream>>>(A_log, sumd, S);
    k_scan3<<<512, 256, 0, stream>>>(x, delta, xp, A_log, Dv, S, y);
}

// Round 5
// 118.779 us; speedup vs baseline: 1.3462x; 1.3462x over previous
//
#include <hip/hip_runtime.h>

// Problem constants
#define BB 2
#define LL 2048
#define DD 2048
#define NS 16      // d_state
#define RK 64      // dt_rank
#define NP 96      // RK + 2*NS
#define NC 32      // chunks
#define CT 64      // L / NC
#define P1_KS 4    // proj1 k-split
#define LOG2E 1.4426950408889634f

#define EXP2F(v) __builtin_amdgcn_exp2f(v)

typedef short bf16x8 __attribute__((ext_vector_type(8)));
typedef float f32x4  __attribute__((ext_vector_type(4)));

// Split 8 f32 into hi/lo bf16 (truncation split: f = hi + lo + O(2^-16 |f|))
__device__ __forceinline__ void split8(float4 a, float4 b, bf16x8& hi, bf16x8& lo) {
    float f[8] = {a.x,a.y,a.z,a.w,b.x,b.y,b.z,b.w};
    #pragma unroll
    for (int i = 0; i < 8; ++i) {
        unsigned u  = __float_as_uint(f[i]);
        unsigned hb = u & 0xffff0000u;
        hi[i] = (short)(hb >> 16);
        float lf = f[i] - __uint_as_float(hb);   // exact
        lo[i] = (short)(__float_as_uint(lf) >> 16);
    }
}

#define MFMA16(acc, a, b) acc = __builtin_amdgcn_mfma_f32_16x16x32_bf16(a, b, acc, 0, 0, 0)
// 3-term split product: hi*hi + hi*lo + lo*hi  (error ~2^-16 relative)
#define MFMA3(acc, ahi, alo, bhi, blo) \
    MFMA16(acc, ahi, bhi); MFMA16(acc, ahi, blo); MFMA16(acc, alo, bhi);

// ---------------------------------------------------------------------------
// K1: partial xp, MFMA bf16-split.  part[ks][r][p] = sum_{k in seg} x[r][k]*Wx[p][k]
// grid (64 M-blocks, 4 k-segs) x 256 thr. Block = 64 rows x 96 cols; wave wv
// owns rows r0+wv*16..+15 (frag row = lane&15, k-group g = lane>>4).
// Wx tile (96x64) split-converted into LDS once per K-step; x read direct
// from global into fragments (each element read exactly once).
// ---------------------------------------------------------------------------
__global__ __launch_bounds__(256) void k_proj1(const float* __restrict__ x,
                                               const float* __restrict__ Wx,
                                               float* __restrict__ part) {
    __shared__ bf16x8 Bhi[8][96];   // [kf*4+g][col], 16B slots -> conflict-free reads
    __shared__ bf16x8 Blo[8][96];
    const int tid  = threadIdx.x;
    const int lane = tid & 63;
    const int wv   = tid >> 6;
    const int l15  = lane & 15;
    const int g    = lane >> 4;
    const int r0   = blockIdx.x * 64;
    const int kb   = blockIdx.y * (DD / P1_KS);     // 512-wide K segment
    const int row  = r0 + wv*16 + l15;

    const f32x4 zero = {0.f, 0.f, 0.f, 0.f};
    f32x4 acc[6];
    #pragma unroll
    for (int ct = 0; ct < 6; ++ct) acc[ct] = zero;

    for (int k0 = kb; k0 < kb + DD/P1_KS; k0 += 64) {
        // stage Wx tile 96x64 -> hi/lo bf16 LDS (768 8-elem chunks, 3/thread)
        #pragma unroll
        for (int i = 0; i < 3; ++i) {
            int c   = tid + i*256;       // 0..767
            int col = c >> 3;
            int kg  = c & 7;             // kf*4+g
            const float4* src = (const float4*)&Wx[(size_t)col*DD + k0 + kg*8];
            bf16x8 hi, lo;
            split8(src[0], src[1], hi, lo);
            Bhi[kg][col] = hi;
            Blo[kg][col] = lo;
        }
        __syncthreads();
        #pragma unroll
        for (int kf = 0; kf < 2; ++kf) {
            const float4* asrc = (const float4*)&x[(size_t)row*DD + k0 + kf*32 + g*8];
            bf16x8 ahi, alo;
            split8(asrc[0], asrc[1], ahi, alo);
            #pragma unroll
            for (int ct = 0; ct < 6; ++ct) {
                bf16x8 bhi = Bhi[kf*4+g][ct*16 + l15];
                bf16x8 blo = Blo[kf*4+g][ct*16 + l15];
                MFMA3(acc[ct], ahi, alo, bhi, blo);
            }
        }
        __syncthreads();
    }
    // C layout: row=(lane>>4)*4+reg, col=lane&15
    float* pout = part + (size_t)blockIdx.y * 4096 * NP;
    #pragma unroll
    for (int ct = 0; ct < 6; ++ct)
        #pragma unroll
        for (int r = 0; r < 4; ++r)
            pout[(size_t)(r0 + wv*16 + g*4 + r)*NP + ct*16 + l15] = acc[ct][r];
}

// ---------------------------------------------------------------------------
// K1b: xp = sum over 4 K-seg partials. 98304 float4s.
// ---------------------------------------------------------------------------
__global__ __launch_bounds__(256) void k_reduce(const float* __restrict__ part,
                                                float* __restrict__ xp) {
    const int i = blockIdx.x*256 + threadIdx.x;   // float4 index, < 98304
    const float4* p = (const float4*)part;
    float4 s = p[i];
    #pragma unroll
    for (int ks = 1; ks < P1_KS; ++ks) {
        float4 v = p[(size_t)ks*98304 + i];
        s.x += v.x; s.y += v.y; s.z += v.z; s.w += v.w;
    }
    ((float4*)xp)[i] = s;
}

// ---------------------------------------------------------------------------
// K2: delta = softplus(delta_p @ Wdt^T + bdt), MFMA bf16-split, NO LDS.
// grid (32, 16) x 256 thr. Block 128x128; wave (wv>>1, wv&1) owns 64x64:
// 4x4 16x16 tiles. A-frags (delta_p = xp[:, :64]) resident in regs; B (Wdt)
// streamed per column-tile. K=64 = 2 kf. Softplus epilogue, coalesced store.
// ---------------------------------------------------------------------------
__global__ __launch_bounds__(256, 2) void k_proj2(const float* __restrict__ xp,
                                                  const float* __restrict__ Wdt,
                                                  const float* __restrict__ bdt,
                                                  float* __restrict__ delta) {
    const int tid  = threadIdx.x;
    const int lane = tid & 63;
    const int wv   = tid >> 6;
    const int l15  = lane & 15;
    const int g    = lane >> 4;
    const int r0   = blockIdx.x * 128 + (wv >> 1) * 64;
    const int d0   = blockIdx.y * 128 + (wv & 1) * 64;

    const f32x4 zero = {0.f, 0.f, 0.f, 0.f};
    f32x4 acc[4][4];
    #pragma unroll
    for (int rt = 0; rt < 4; ++rt)
        #pragma unroll
        for (int ct = 0; ct < 4; ++ct) acc[rt][ct] = zero;

    // A-frags resident: [kf][rt]
    bf16x8 ahi[2][4], alo[2][4];
    #pragma unroll
    for (int kf = 0; kf < 2; ++kf)
        #pragma unroll
        for (int rt = 0; rt < 4; ++rt) {
            const float4* s = (const float4*)&xp[(size_t)(r0 + rt*16 + l15)*NP + kf*32 + g*8];
            split8(s[0], s[1], ahi[kf][rt], alo[kf][rt]);
        }

    #pragma unroll
    for (int ct = 0; ct < 4; ++ct) {
        #pragma unroll
        for (int kf = 0; kf < 2; ++kf) {
            const float4* s = (const float4*)&Wdt[(size_t)(d0 + ct*16 + l15)*RK + kf*32 + g*8];
            bf16x8 bhi, blo;
            split8(s[0], s[1], bhi, blo);
            #pragma unroll
            for (int rt = 0; rt < 4; ++rt) {
                MFMA3(acc[rt][ct], ahi[kf][rt], alo[kf][rt], bhi, blo);
            }
        }
    }

    // epilogue: softplus + store (lanes of a 16-group write consecutive d)
    #pragma unroll
    for (int ct = 0; ct < 4; ++ct) {
        const float bd = bdt[d0 + ct*16 + l15];
        #pragma unroll
        for (int rt = 0; rt < 4; ++rt) {
            #pragma unroll
            for (int r = 0; r < 4; ++r) {
                float z  = acc[rt][ct][r] + bd;
                float sp = (z > 15.f) ? z : __logf(1.f + __expf(z));
                delta[(size_t)(r0 + rt*16 + g*4 + r)*DD + d0 + ct*16 + l15] = sp;
            }
        }
    }
}

// ---------------------------------------------------------------------------
// K3 (pass 1): per (b, chunk, d): chunk scan from h=0 -> S[b][c][n][d], sumdelta.
// ---------------------------------------------------------------------------
__global__ __launch_bounds__(256) void k_scan1(const float* __restrict__ x,
                                               const float* __restrict__ delta,
                                               const float* __restrict__ xp,
                                               const float* __restrict__ A_log,
                                               float* __restrict__ S,
                                               float* __restrict__ sumdelta) {
    const int bid = blockIdx.x;          // b*256 + c*8 + dq
    const int dq = bid & 7;
    const int c  = (bid >> 3) & (NC-1);
    const int b  = bid >> 8;
    const int d  = dq*256 + threadIdx.x;

    float A2[NS];
    {
        const float4* Ar = (const float4*)&A_log[(size_t)d*NS];
        #pragma unroll
        for (int q = 0; q < 4; ++q) {
            float4 v = Ar[q];
            A2[q*4+0] = -__expf(v.x) * LOG2E;
            A2[q*4+1] = -__expf(v.y) * LOG2E;
            A2[q*4+2] = -__expf(v.z) * LOG2E;
            A2[q*4+3] = -__expf(v.w) * LOG2E;
        }
    }
    float h[NS];
    #pragma unroll
    for (int n = 0; n < NS; ++n) h[n] = 0.f;
    float sd = 0.f;

    const int t0 = c * CT;
    size_t base = ((size_t)b*LL + t0)*DD + d;
    for (int t = t0; t < t0 + CT; ++t) {
        float dlt = delta[base];
        float xv  = x[base];
        sd += dlt;
        float dx = dlt * xv;
        const float4* Bp4 = (const float4*)&xp[((size_t)b*LL + t)*NP + RK];
        float bp[NS];
        *(float4*)&bp[0]  = Bp4[0];
        *(float4*)&bp[4]  = Bp4[1];
        *(float4*)&bp[8]  = Bp4[2];
        *(float4*)&bp[12] = Bp4[3];
        #pragma unroll
        for (int n = 0; n < NS; ++n)
            h[n] = EXP2F(A2[n]*dlt)*h[n] + dx*bp[n];
        base += DD;
    }
    size_t so = ((size_t)(b*NC + c)*NS)*DD + d;
    #pragma unroll
    for (int n = 0; n < NS; ++n) S[so + (size_t)n*DD] = h[n];
    sumdelta[((size_t)(b*NC + c))*DD + d] = sd;
}

// ---------------------------------------------------------------------------
// K4 (pass 2): cross-chunk recurrence, in place: S[c] <- state ENTERING chunk c.
// ---------------------------------------------------------------------------
__global__ __launch_bounds__(256) void k_scan2(const float* __restrict__ A_log,
                                               const float* __restrict__ sumdelta,
                                               float* __restrict__ S) {
    const int g = blockIdx.x*256 + threadIdx.x;   // (b*16+n)*2048 + d
    const int d = g & (DD-1);
    const int n = (g >> 11) & (NS-1);
    const int b = g >> 15;
    const float A2 = -__expf(A_log[(size_t)d*NS + n]) * LOG2E;
    float carry = 0.f;
    for (int c = 0; c < NC; ++c) {
        size_t si = ((size_t)(b*NC + c)*NS + n)*DD + d;
        float s  = S[si];
        float sd = sumdelta[((size_t)(b*NC + c))*DD + d];
        S[si] = carry;                       // state entering chunk c
        carry = EXP2F(A2*sd)*carry + s;      // state after chunk c
    }
}

// ---------------------------------------------------------------------------
// K5 (pass 3): replay each chunk from its true incoming state, emit y.
// ---------------------------------------------------------------------------
__global__ __launch_bounds__(256) void k_scan3(const float* __restrict__ x,
                                               const float* __restrict__ delta,
                                               const float* __restrict__ xp,
                                               const float* __restrict__ A_log,
                                               const float* __restrict__ Dv,
                                               const float* __restrict__ S,
                                               float* __restrict__ y) {
    const int bid = blockIdx.x;
    const int dq = bid & 7;
    const int c  = (bid >> 3) & (NC-1);
    const int b  = bid >> 8;
    const int d  = dq*256 + threadIdx.x;

    float A2[NS];
    {
        const float4* Ar = (const float4*)&A_log[(size_t)d*NS];
        #pragma unroll
        for (int q = 0; q < 4; ++q) {
            float4 v = Ar[q];
            A2[q*4+0] = -__expf(v.x) * LOG2E;
            A2[q*4+1] = -__expf(v.y) * LOG2E;
            A2[q*4+2] = -__expf(v.z) * LOG2E;
            A2[q*4+3] = -__expf(v.w) * LOG2E;
        }
    }
    float h[NS];
    size_t so = ((size_t)(b*NC + c)*NS)*DD + d;
    #pragma unroll
    for (int n = 0; n < NS; ++n) h[n] = S[so + (size_t)n*DD];
    const float Dd = Dv[d];

    const int t0 = c * CT;
    size_t base = ((size_t)b*LL + t0)*DD + d;
    for (int t = t0; t < t0 + CT; ++t) {
        float dlt = delta[base];
        float xv  = x[base];
        float dx = dlt * xv;
        const float4* Pr = (const float4*)&xp[((size_t)b*LL + t)*NP + RK];
        float bp[NS], cp[NS];
        *(float4*)&bp[0]  = Pr[0];
        *(float4*)&bp[4]  = Pr[1];
        *(float4*)&bp[8]  = Pr[2];
        *(float4*)&bp[12] = Pr[3];
        *(float4*)&cp[0]  = Pr[4];   // C_proj = xp[:, 80:96]
        *(float4*)&cp[4]  = Pr[5];
        *(float4*)&cp[8]  = Pr[6];
        *(float4*)&cp[12] = Pr[7];
        float yt = 0.f;
        #pragma unroll
        for (int n = 0; n < NS; ++n) {
            h[n] = EXP2F(A2[n]*dlt)*h[n] + dx*bp[n];
            yt += h[n]*cp[n];
        }
        y[base] = yt + xv*Dd;
        base += DD;
    }
}

// ---------------------------------------------------------------------------
extern "C" void kernel_launch(void* const* d_in, const int* in_sizes, int n_in,
                              void* d_out, int out_size, void* d_ws, size_t ws_size,
                              hipStream_t stream) {
    const float* x     = (const float*)d_in[0];
    const float* A_log = (const float*)d_in[1];
    const float* Dv    = (const float*)d_in[2];
    const float* Wx    = (const float*)d_in[3];
    const float* Wdt   = (const float*)d_in[4];
    const float* bdt   = (const float*)d_in[5];
    float* y = (float*)d_out;

    // ws layout (floats): xp[4096*96] | delta[4096*2048] | S[2*32*16*2048] | sumdelta[2*32*2048]
    // proj1 partials (4*4096*96 floats = 6.3 MB) alias the delta region;
    // delta itself is written (by proj2) only after k_reduce has consumed them.
    float* ws    = (float*)d_ws;
    float* xp    = ws;
    float* delta = xp + (size_t)4096*NP;
    float* S     = delta + (size_t)4096*DD;
    float* sumd  = S + (size_t)BB*NC*NS*DD;
    float* part  = delta;

    k_proj1<<<dim3(64, P1_KS), 256, 0, stream>>>(x, Wx, part);
    k_reduce<<<384, 256, 0, stream>>>(part, xp);
    k_proj2<<<dim3(32, 16), 256, 0, stream>>>(xp, Wdt, bdt, delta);
    k_scan1<<<512, 256, 0, stream>>>(x, delta, xp, A_log, S, sumd);
    k_scan2<<<256, 256, 0, stream>>>(A_log, sumd, S);
    k_scan3<<<512, 256, 0, stream>>>(x, delta, xp, A_log, Dv, S, y);
}

// Round 6
// 115.977 us; speedup vs baseline: 1.3787x; 1.0242x over previous
//
#include <hip/hip_runtime.h>

// Problem constants
#define BB 2
#define LL 2048
#define DD 2048
#define NS 16      // d_state
#define RK 64      // dt_rank
#define NP 96      // RK + 2*NS
#define NC 64      // chunks
#define CT 32      // L / NC
#define P1_KS 4    // proj1 k-split
#define LOG2E 1.4426950408889634f

#define EXP2F(v) __builtin_amdgcn_exp2f(v)

typedef short bf16x8 __attribute__((ext_vector_type(8)));
typedef float f32x4  __attribute__((ext_vector_type(4)));

// Split 8 f32 into hi/lo bf16 (truncation split: f = hi + lo + O(2^-16 |f|))
__device__ __forceinline__ void split8(float4 a, float4 b, bf16x8& hi, bf16x8& lo) {
    float f[8] = {a.x,a.y,a.z,a.w,b.x,b.y,b.z,b.w};
    #pragma unroll
    for (int i = 0; i < 8; ++i) {
        unsigned u  = __float_as_uint(f[i]);
        unsigned hb = u & 0xffff0000u;
        hi[i] = (short)(hb >> 16);
        float lf = f[i] - __uint_as_float(hb);   // exact
        lo[i] = (short)(__float_as_uint(lf) >> 16);
    }
}

#define MFMA16(acc, a, b) acc = __builtin_amdgcn_mfma_f32_16x16x32_bf16(a, b, acc, 0, 0, 0)
// 3-term split product: hi*hi + hi*lo + lo*hi  (error ~2^-16 relative)
#define MFMA3(acc, ahi, alo, bhi, blo) \
    MFMA16(acc, ahi, bhi); MFMA16(acc, ahi, blo); MFMA16(acc, alo, bhi);

// ---------------------------------------------------------------------------
// K1: partial xp, MFMA bf16-split.  part[ks][r][p] = sum_{k in seg} x[r][k]*Wx[p][k]
// grid (64 M-blocks, 4 k-segs) x 256 thr. Block = 64 rows x 96 cols; wave wv
// owns rows r0+wv*16..+15. Wx tile split-converted into LDS once per K-step;
// x read direct from global into fragments (each element read exactly once).
// ---------------------------------------------------------------------------
__global__ __launch_bounds__(256) void k_proj1(const float* __restrict__ x,
                                               const float* __restrict__ Wx,
                                               float* __restrict__ part) {
    __shared__ bf16x8 Bhi[8][96];   // [kf*4+g][col], 16B slots -> conflict-free reads
    __shared__ bf16x8 Blo[8][96];
    const int tid  = threadIdx.x;
    const int lane = tid & 63;
    const int wv   = tid >> 6;
    const int l15  = lane & 15;
    const int g    = lane >> 4;
    const int r0   = blockIdx.x * 64;
    const int kb   = blockIdx.y * (DD / P1_KS);     // 512-wide K segment
    const int row  = r0 + wv*16 + l15;

    const f32x4 zero = {0.f, 0.f, 0.f, 0.f};
    f32x4 acc[6];
    #pragma unroll
    for (int ct = 0; ct < 6; ++ct) acc[ct] = zero;

    for (int k0 = kb; k0 < kb + DD/P1_KS; k0 += 64) {
        // stage Wx tile 96x64 -> hi/lo bf16 LDS (768 8-elem chunks, 3/thread)
        #pragma unroll
        for (int i = 0; i < 3; ++i) {
            int c   = tid + i*256;       // 0..767
            int col = c >> 3;
            int kg  = c & 7;             // kf*4+g
            const float4* src = (const float4*)&Wx[(size_t)col*DD + k0 + kg*8];
            bf16x8 hi, lo;
            split8(src[0], src[1], hi, lo);
            Bhi[kg][col] = hi;
            Blo[kg][col] = lo;
        }
        __syncthreads();
        #pragma unroll
        for (int kf = 0; kf < 2; ++kf) {
            const float4* asrc = (const float4*)&x[(size_t)row*DD + k0 + kf*32 + g*8];
            bf16x8 ahi, alo;
            split8(asrc[0], asrc[1], ahi, alo);
            #pragma unroll
            for (int ct = 0; ct < 6; ++ct) {
                bf16x8 bhi = Bhi[kf*4+g][ct*16 + l15];
                bf16x8 blo = Blo[kf*4+g][ct*16 + l15];
                MFMA3(acc[ct], ahi, alo, bhi, blo);
            }
        }
        __syncthreads();
    }
    // C layout: row=(lane>>4)*4+reg, col=lane&15
    float* pout = part + (size_t)blockIdx.y * 4096 * NP;
    #pragma unroll
    for (int ct = 0; ct < 6; ++ct)
        #pragma unroll
        for (int r = 0; r < 4; ++r)
            pout[(size_t)(r0 + wv*16 + g*4 + r)*NP + ct*16 + l15] = acc[ct][r];
}

// ---------------------------------------------------------------------------
// K1b: xp = sum over 4 K-seg partials. 98304 float4s.
// ---------------------------------------------------------------------------
__global__ __launch_bounds__(256) void k_reduce(const float* __restrict__ part,
                                                float* __restrict__ xp) {
    const int i = blockIdx.x*256 + threadIdx.x;   // float4 index, < 98304
    const float4* p = (const float4*)part;
    float4 s = p[i];
    #pragma unroll
    for (int ks = 1; ks < P1_KS; ++ks) {
        float4 v = p[(size_t)ks*98304 + i];
        s.x += v.x; s.y += v.y; s.z += v.z; s.w += v.w;
    }
    ((float4*)xp)[i] = s;
}

// ---------------------------------------------------------------------------
// K2: delta = softplus(delta_p @ Wdt^T + bdt), MFMA bf16-split, NO LDS.
// grid (32, 16) x 256 thr. Block 128x128; wave (wv>>1, wv&1) owns 64x64.
// ---------------------------------------------------------------------------
__global__ __launch_bounds__(256, 2) void k_proj2(const float* __restrict__ xp,
                                                  const float* __restrict__ Wdt,
                                                  const float* __restrict__ bdt,
                                                  float* __restrict__ delta) {
    const int tid  = threadIdx.x;
    const int lane = tid & 63;
    const int wv   = tid >> 6;
    const int l15  = lane & 15;
    const int g    = lane >> 4;
    const int r0   = blockIdx.x * 128 + (wv >> 1) * 64;
    const int d0   = blockIdx.y * 128 + (wv & 1) * 64;

    const f32x4 zero = {0.f, 0.f, 0.f, 0.f};
    f32x4 acc[4][4];
    #pragma unroll
    for (int rt = 0; rt < 4; ++rt)
        #pragma unroll
        for (int ct = 0; ct < 4; ++ct) acc[rt][ct] = zero;

    // A-frags resident: [kf][rt]
    bf16x8 ahi[2][4], alo[2][4];
    #pragma unroll
    for (int kf = 0; kf < 2; ++kf)
        #pragma unroll
        for (int rt = 0; rt < 4; ++rt) {
            const float4* s = (const float4*)&xp[(size_t)(r0 + rt*16 + l15)*NP + kf*32 + g*8];
            split8(s[0], s[1], ahi[kf][rt], alo[kf][rt]);
        }

    #pragma unroll
    for (int ct = 0; ct < 4; ++ct) {
        #pragma unroll
        for (int kf = 0; kf < 2; ++kf) {
            const float4* s = (const float4*)&Wdt[(size_t)(d0 + ct*16 + l15)*RK + kf*32 + g*8];
            bf16x8 bhi, blo;
            split8(s[0], s[1], bhi, blo);
            #pragma unroll
            for (int rt = 0; rt < 4; ++rt) {
                MFMA3(acc[rt][ct], ahi[kf][rt], alo[kf][rt], bhi, blo);
            }
        }
    }

    // epilogue: softplus + store (lanes of a 16-group write consecutive d)
    #pragma unroll
    for (int ct = 0; ct < 4; ++ct) {
        const float bd = bdt[d0 + ct*16 + l15];
        #pragma unroll
        for (int rt = 0; rt < 4; ++rt) {
            #pragma unroll
            for (int r = 0; r < 4; ++r) {
                float z  = acc[rt][ct][r] + bd;
                float sp = (z > 15.f) ? z : __logf(1.f + __expf(z));
                delta[(size_t)(r0 + rt*16 + g*4 + r)*DD + d0 + ct*16 + l15] = sp;
            }
        }
    }
}

// ---------------------------------------------------------------------------
// K3 (pass 1): per (b, chunk, d): chunk scan from h=0 -> S[b][c][n][d], sumdelta.
// grid 1024 x 256. Prefetched t-loop (1-ahead on delta/x).
// ---------------------------------------------------------------------------
__global__ __launch_bounds__(256) void k_scan1(const float* __restrict__ x,
                                               const float* __restrict__ delta,
                                               const float* __restrict__ xp,
                                               const float* __restrict__ A_log,
                                               float* __restrict__ S,
                                               float* __restrict__ sumdelta) {
    const int bid = blockIdx.x;          // b*512 + c*8 + dq
    const int dq = bid & 7;
    const int c  = (bid >> 3) & (NC-1);
    const int b  = bid >> 9;
    const int d  = dq*256 + threadIdx.x;

    float A2[NS];
    {
        const float4* Ar = (const float4*)&A_log[(size_t)d*NS];
        #pragma unroll
        for (int q = 0; q < 4; ++q) {
            float4 v = Ar[q];
            A2[q*4+0] = -__expf(v.x) * LOG2E;
            A2[q*4+1] = -__expf(v.y) * LOG2E;
            A2[q*4+2] = -__expf(v.z) * LOG2E;
            A2[q*4+3] = -__expf(v.w) * LOG2E;
        }
    }
    float h[NS];
    #pragma unroll
    for (int n = 0; n < NS; ++n) h[n] = 0.f;
    float sd = 0.f;

    const int t0 = c * CT;
    size_t base = ((size_t)b*LL + t0)*DD + d;
    const float* xpb = &xp[((size_t)b*LL + t0)*NP + RK];

    float dlt = delta[base];
    float xv  = x[base];
    for (int tt = 0; tt < CT; ++tt) {
        const size_t nb = base + ((tt+1 < CT) ? DD : 0);   // clamped prefetch addr
        float dlt_n = delta[nb];
        float xv_n  = x[nb];
        float bp[NS];
        *(float4*)&bp[0]  = *(const float4*)&xpb[0];
        *(float4*)&bp[4]  = *(const float4*)&xpb[4];
        *(float4*)&bp[8]  = *(const float4*)&xpb[8];
        *(float4*)&bp[12] = *(const float4*)&xpb[12];
        sd += dlt;
        float dx = dlt * xv;
        #pragma unroll
        for (int n = 0; n < NS; ++n)
            h[n] = EXP2F(A2[n]*dlt)*h[n] + dx*bp[n];
        dlt = dlt_n; xv = xv_n;
        base += DD; xpb += NP;
    }
    size_t so = ((size_t)(b*NC + c)*NS)*DD + d;
    #pragma unroll
    for (int n = 0; n < NS; ++n) S[so + (size_t)n*DD] = h[n];
    sumdelta[((size_t)(b*NC + c))*DD + d] = sd;
}

// ---------------------------------------------------------------------------
// K4 (pass 2): cross-chunk recurrence, in place: S[c] <- state ENTERING chunk c.
// ---------------------------------------------------------------------------
__global__ __launch_bounds__(256) void k_scan2(const float* __restrict__ A_log,
                                               const float* __restrict__ sumdelta,
                                               float* __restrict__ S) {
    const int g = blockIdx.x*256 + threadIdx.x;   // (b*16+n)*2048 + d
    const int d = g & (DD-1);
    const int n = (g >> 11) & (NS-1);
    const int b = g >> 15;
    const float A2 = -__expf(A_log[(size_t)d*NS + n]) * LOG2E;
    float carry = 0.f;
    for (int c = 0; c < NC; ++c) {
        size_t si = ((size_t)(b*NC + c)*NS + n)*DD + d;
        float s  = S[si];
        float sd = sumdelta[((size_t)(b*NC + c))*DD + d];
        S[si] = carry;                       // state entering chunk c
        carry = EXP2F(A2*sd)*carry + s;      // state after chunk c
    }
}

// ---------------------------------------------------------------------------
// K5 (pass 3): replay each chunk from its true incoming state, emit y.
// grid 1024 x 256. Prefetched t-loop.
// ---------------------------------------------------------------------------
__global__ __launch_bounds__(256) void k_scan3(const float* __restrict__ x,
                                               const float* __restrict__ delta,
                                               const float* __restrict__ xp,
                                               const float* __restrict__ A_log,
                                               const float* __restrict__ Dv,
                                               const float* __restrict__ S,
                                               float* __restrict__ y) {
    const int bid = blockIdx.x;
    const int dq = bid & 7;
    const int c  = (bid >> 3) & (NC-1);
    const int b  = bid >> 9;
    const int d  = dq*256 + threadIdx.x;

    float A2[NS];
    {
        const float4* Ar = (const float4*)&A_log[(size_t)d*NS];
        #pragma unroll
        for (int q = 0; q < 4; ++q) {
            float4 v = Ar[q];
            A2[q*4+0] = -__expf(v.x) * LOG2E;
            A2[q*4+1] = -__expf(v.y) * LOG2E;
            A2[q*4+2] = -__expf(v.z) * LOG2E;
            A2[q*4+3] = -__expf(v.w) * LOG2E;
        }
    }
    float h[NS];
    size_t so = ((size_t)(b*NC + c)*NS)*DD + d;
    #pragma unroll
    for (int n = 0; n < NS; ++n) h[n] = S[so + (size_t)n*DD];
    const float Dd = Dv[d];

    const int t0 = c * CT;
    size_t base = ((size_t)b*LL + t0)*DD + d;
    const float* xpb = &xp[((size_t)b*LL + t0)*NP + RK];

    float dlt = delta[base];
    float xv  = x[base];
    for (int tt = 0; tt < CT; ++tt) {
        const size_t nb = base + ((tt+1 < CT) ? DD : 0);
        float dlt_n = delta[nb];
        float xv_n  = x[nb];
        float bp[NS], cp[NS];
        *(float4*)&bp[0]  = *(const float4*)&xpb[0];
        *(float4*)&bp[4]  = *(const float4*)&xpb[4];
        *(float4*)&bp[8]  = *(const float4*)&xpb[8];
        *(float4*)&bp[12] = *(const float4*)&xpb[12];
        *(float4*)&cp[0]  = *(const float4*)&xpb[16];   // C_proj = xp[:, 80:96]
        *(float4*)&cp[4]  = *(const float4*)&xpb[20];
        *(float4*)&cp[8]  = *(const float4*)&xpb[24];
        *(float4*)&cp[12] = *(const float4*)&xpb[28];
        float dx = dlt * xv;
        float yt = 0.f;
        #pragma unroll
        for (int n = 0; n < NS; ++n) {
            h[n] = EXP2F(A2[n]*dlt)*h[n] + dx*bp[n];
            yt += h[n]*cp[n];
        }
        y[base] = yt + xv*Dd;
        dlt = dlt_n; xv = xv_n;
        base += DD; xpb += NP;
    }
}

// ---------------------------------------------------------------------------
extern "C" void kernel_launch(void* const* d_in, const int* in_sizes, int n_in,
                              void* d_out, int out_size, void* d_ws, size_t ws_size,
                              hipStream_t stream) {
    const float* x     = (const float*)d_in[0];
    const float* A_log = (const float*)d_in[1];
    const float* Dv    = (const float*)d_in[2];
    const float* Wx    = (const float*)d_in[3];
    const float* Wdt   = (const float*)d_in[4];
    const float* bdt   = (const float*)d_in[5];
    float* y = (float*)d_out;

    // ws layout (floats): xp[4096*96] | delta[4096*2048] | S[2*64*16*2048] | sumdelta[2*64*2048]
    // proj1 partials (4*4096*96 floats) alias the delta region; delta itself is
    // written (by proj2) only after k_reduce has consumed them.  ~53 MB total.
    float* ws    = (float*)d_ws;
    float* xp    = ws;
    float* delta = xp + (size_t)4096*NP;
    float* S     = delta + (size_t)4096*DD;
    float* sumd  = S + (size_t)BB*NC*NS*DD;
    float* part  = delta;

    k_proj1<<<dim3(64, P1_KS), 256, 0, stream>>>(x, Wx, part);
    k_reduce<<<384, 256, 0, stream>>>(part, xp);
    k_proj2<<<dim3(32, 16), 256, 0, stream>>>(xp, Wdt, bdt, delta);
    k_scan1<<<1024, 256, 0, stream>>>(x, delta, xp, A_log, S, sumd);
    k_scan2<<<256, 256, 0, stream>>>(A_log, sumd, S);
    k_scan3<<<1024, 256, 0, stream>>>(x, delta, xp, A_log, Dv, S, y);
}

// Round 7
// 114.225 us; speedup vs baseline: 1.3998x; 1.0153x over previous
//
#include <hip/hip_runtime.h>

// Problem constants
#define BB 2
#define LL 2048
#define DD 2048
#define NS 16      // d_state
#define RK 64      // dt_rank
#define NP 96      // RK + 2*NS
#define NC 64      // chunks
#define CT 32      // L / NC
#define P1_KS 4    // proj1 k-split
#define LOG2E 1.4426950408889634f

#define EXP2F(v) __builtin_amdgcn_exp2f(v)

typedef short bf16x8 __attribute__((ext_vector_type(8)));
typedef float f32x4  __attribute__((ext_vector_type(4)));

// Split 8 f32 into hi/lo bf16 (truncation split: f = hi + lo + O(2^-16 |f|))
__device__ __forceinline__ void split8(float4 a, float4 b, bf16x8& hi, bf16x8& lo) {
    float f[8] = {a.x,a.y,a.z,a.w,b.x,b.y,b.z,b.w};
    #pragma unroll
    for (int i = 0; i < 8; ++i) {
        unsigned u  = __float_as_uint(f[i]);
        unsigned hb = u & 0xffff0000u;
        hi[i] = (short)(hb >> 16);
        float lf = f[i] - __uint_as_float(hb);   // exact
        lo[i] = (short)(__float_as_uint(lf) >> 16);
    }
}

#define MFMA16(acc, a, b) acc = __builtin_amdgcn_mfma_f32_16x16x32_bf16(a, b, acc, 0, 0, 0)
// 3-term split product: hi*hi + hi*lo + lo*hi  (error ~2^-16 relative)
#define MFMA3(acc, ahi, alo, bhi, blo) \
    MFMA16(acc, ahi, bhi); MFMA16(acc, ahi, blo); MFMA16(acc, alo, bhi);

// ---------------------------------------------------------------------------
// K1: partial xp, MFMA bf16-split.  part[ks][r][p] = sum_{k in seg} x[r][k]*Wx[p][k]
// grid (64 M-blocks, 4 k-segs) x 256 thr. Block = 64 rows x 96 cols.
// ---------------------------------------------------------------------------
__global__ __launch_bounds__(256) void k_proj1(const float* __restrict__ x,
                                               const float* __restrict__ Wx,
                                               float* __restrict__ part) {
    __shared__ bf16x8 Bhi[8][96];   // [kf*4+g][col], 16B slots -> conflict-free reads
    __shared__ bf16x8 Blo[8][96];
    const int tid  = threadIdx.x;
    const int lane = tid & 63;
    const int wv   = tid >> 6;
    const int l15  = lane & 15;
    const int g    = lane >> 4;
    const int r0   = blockIdx.x * 64;
    const int kb   = blockIdx.y * (DD / P1_KS);     // 512-wide K segment
    const int row  = r0 + wv*16 + l15;

    const f32x4 zero = {0.f, 0.f, 0.f, 0.f};
    f32x4 acc[6];
    #pragma unroll
    for (int ct = 0; ct < 6; ++ct) acc[ct] = zero;

    for (int k0 = kb; k0 < kb + DD/P1_KS; k0 += 64) {
        // stage Wx tile 96x64 -> hi/lo bf16 LDS (768 8-elem chunks, 3/thread)
        #pragma unroll
        for (int i = 0; i < 3; ++i) {
            int c   = tid + i*256;       // 0..767
            int col = c >> 3;
            int kg  = c & 7;             // kf*4+g
            const float4* src = (const float4*)&Wx[(size_t)col*DD + k0 + kg*8];
            bf16x8 hi, lo;
            split8(src[0], src[1], hi, lo);
            Bhi[kg][col] = hi;
            Blo[kg][col] = lo;
        }
        __syncthreads();
        #pragma unroll
        for (int kf = 0; kf < 2; ++kf) {
            const float4* asrc = (const float4*)&x[(size_t)row*DD + k0 + kf*32 + g*8];
            bf16x8 ahi, alo;
            split8(asrc[0], asrc[1], ahi, alo);
            #pragma unroll
            for (int ct = 0; ct < 6; ++ct) {
                bf16x8 bhi = Bhi[kf*4+g][ct*16 + l15];
                bf16x8 blo = Blo[kf*4+g][ct*16 + l15];
                MFMA3(acc[ct], ahi, alo, bhi, blo);
            }
        }
        __syncthreads();
    }
    // C layout: row=(lane>>4)*4+reg, col=lane&15
    float* pout = part + (size_t)blockIdx.y * 4096 * NP;
    #pragma unroll
    for (int ct = 0; ct < 6; ++ct)
        #pragma unroll
        for (int r = 0; r < 4; ++r)
            pout[(size_t)(r0 + wv*16 + g*4 + r)*NP + ct*16 + l15] = acc[ct][r];
}

// ---------------------------------------------------------------------------
// K1b: xp = sum over 4 K-seg partials. 98304 float4s.
// ---------------------------------------------------------------------------
__global__ __launch_bounds__(256) void k_reduce(const float* __restrict__ part,
                                                float* __restrict__ xp) {
    const int i = blockIdx.x*256 + threadIdx.x;   // float4 index, < 98304
    const float4* p = (const float4*)part;
    float4 s = p[i];
    #pragma unroll
    for (int ks = 1; ks < P1_KS; ++ks) {
        float4 v = p[(size_t)ks*98304 + i];
        s.x += v.x; s.y += v.y; s.z += v.z; s.w += v.w;
    }
    ((float4*)xp)[i] = s;
}

// ---------------------------------------------------------------------------
// K2: delta = softplus(delta_p @ Wdt^T + bdt), MFMA bf16-split, NO LDS.
// grid (32, 16) x 256 thr. Block 128x128; wave (wv>>1, wv&1) owns 64x64.
// ---------------------------------------------------------------------------
__global__ __launch_bounds__(256, 2) void k_proj2(const float* __restrict__ xp,
                                                  const float* __restrict__ Wdt,
                                                  const float* __restrict__ bdt,
                                                  float* __restrict__ delta) {
    const int tid  = threadIdx.x;
    const int lane = tid & 63;
    const int wv   = tid >> 6;
    const int l15  = lane & 15;
    const int g    = lane >> 4;
    const int r0   = blockIdx.x * 128 + (wv >> 1) * 64;
    const int d0   = blockIdx.y * 128 + (wv & 1) * 64;

    const f32x4 zero = {0.f, 0.f, 0.f, 0.f};
    f32x4 acc[4][4];
    #pragma unroll
    for (int rt = 0; rt < 4; ++rt)
        #pragma unroll
        for (int ct = 0; ct < 4; ++ct) acc[rt][ct] = zero;

    // A-frags resident: [kf][rt]
    bf16x8 ahi[2][4], alo[2][4];
    #pragma unroll
    for (int kf = 0; kf < 2; ++kf)
        #pragma unroll
        for (int rt = 0; rt < 4; ++rt) {
            const float4* s = (const float4*)&xp[(size_t)(r0 + rt*16 + l15)*NP + kf*32 + g*8];
            split8(s[0], s[1], ahi[kf][rt], alo[kf][rt]);
        }

    #pragma unroll
    for (int ct = 0; ct < 4; ++ct) {
        #pragma unroll
        for (int kf = 0; kf < 2; ++kf) {
            const float4* s = (const float4*)&Wdt[(size_t)(d0 + ct*16 + l15)*RK + kf*32 + g*8];
            bf16x8 bhi, blo;
            split8(s[0], s[1], bhi, blo);
            #pragma unroll
            for (int rt = 0; rt < 4; ++rt) {
                MFMA3(acc[rt][ct], ahi[kf][rt], alo[kf][rt], bhi, blo);
            }
        }
    }

    // epilogue: softplus + store (lanes of a 16-group write consecutive d)
    #pragma unroll
    for (int ct = 0; ct < 4; ++ct) {
        const float bd = bdt[d0 + ct*16 + l15];
        #pragma unroll
        for (int rt = 0; rt < 4; ++rt) {
            #pragma unroll
            for (int r = 0; r < 4; ++r) {
                float z  = acc[rt][ct][r] + bd;
                float sp = (z > 15.f) ? z : __logf(1.f + __expf(z));
                delta[(size_t)(r0 + rt*16 + g*4 + r)*DD + d0 + ct*16 + l15] = sp;
            }
        }
    }
}

// ---------------------------------------------------------------------------
// K3 (pass 1): per (b, chunk, d): chunk scan from h=0 -> S[b][c][n][d], sumdelta.
// grid 1024 x 256. FULL 1-ahead pipeline: delta, x, AND the 4 xp float4s.
// ---------------------------------------------------------------------------
__global__ __launch_bounds__(256) void k_scan1(const float* __restrict__ x,
                                               const float* __restrict__ delta,
                                               const float* __restrict__ xp,
                                               const float* __restrict__ A_log,
                                               float* __restrict__ S,
                                               float* __restrict__ sumdelta) {
    const int bid = blockIdx.x;          // b*512 + c*8 + dq
    const int dq = bid & 7;
    const int c  = (bid >> 3) & (NC-1);
    const int b  = bid >> 9;
    const int d  = dq*256 + threadIdx.x;

    float A2[NS];
    {
        const float4* Ar = (const float4*)&A_log[(size_t)d*NS];
        #pragma unroll
        for (int q = 0; q < 4; ++q) {
            float4 v = Ar[q];
            A2[q*4+0] = -__expf(v.x) * LOG2E;
            A2[q*4+1] = -__expf(v.y) * LOG2E;
            A2[q*4+2] = -__expf(v.z) * LOG2E;
            A2[q*4+3] = -__expf(v.w) * LOG2E;
        }
    }
    float h[NS];
    #pragma unroll
    for (int n = 0; n < NS; ++n) h[n] = 0.f;
    float sd = 0.f;

    const int t0 = c * CT;
    size_t base = ((size_t)b*LL + t0)*DD + d;
    const float* xpb = &xp[((size_t)b*LL + t0)*NP + RK];

    float dlt = delta[base];
    float xv  = x[base];
    float4 bpv[4];
    #pragma unroll
    for (int q = 0; q < 4; ++q) bpv[q] = *(const float4*)&xpb[q*4];

    for (int tt = 0; tt < CT; ++tt) {
        const int ok = (tt+1 < CT);
        const size_t nb = base + (ok ? DD : 0);           // clamped prefetch addr
        const float* xpn = xpb + (ok ? NP : 0);
        float dlt_n = delta[nb];
        float xv_n  = x[nb];
        float4 bpn[4];
        #pragma unroll
        for (int q = 0; q < 4; ++q) bpn[q] = *(const float4*)&xpn[q*4];

        sd += dlt;
        float dx = dlt * xv;
        const float* bp = (const float*)bpv;
        #pragma unroll
        for (int n = 0; n < NS; ++n)
            h[n] = EXP2F(A2[n]*dlt)*h[n] + dx*bp[n];

        dlt = dlt_n; xv = xv_n;
        #pragma unroll
        for (int q = 0; q < 4; ++q) bpv[q] = bpn[q];
        base += DD; xpb += NP;
    }
    size_t so = ((size_t)(b*NC + c)*NS)*DD + d;
    #pragma unroll
    for (int n = 0; n < NS; ++n) S[so + (size_t)n*DD] = h[n];
    sumdelta[((size_t)(b*NC + c))*DD + d] = sd;
}

// ---------------------------------------------------------------------------
// K4 (pass 2): cross-chunk recurrence, in place: S[c] <- state ENTERING chunk c.
// 1-ahead prefetch on S and sumdelta.
// ---------------------------------------------------------------------------
__global__ __launch_bounds__(256) void k_scan2(const float* __restrict__ A_log,
                                               const float* __restrict__ sumdelta,
                                               float* __restrict__ S) {
    const int g = blockIdx.x*256 + threadIdx.x;   // (b*16+n)*2048 + d
    const int d = g & (DD-1);
    const int n = (g >> 11) & (NS-1);
    const int b = g >> 15;
    const float A2 = -__expf(A_log[(size_t)d*NS + n]) * LOG2E;
    float carry = 0.f;
    size_t si = ((size_t)(b*NC + 0)*NS + n)*DD + d;
    size_t di = ((size_t)(b*NC + 0))*DD + d;
    float s  = S[si];
    float sd = sumdelta[di];
    for (int c = 0; c < NC; ++c) {
        const int ok = (c+1 < NC);
        const size_t sin = si + (ok ? (size_t)NS*DD : 0);
        const size_t din = di + (ok ? (size_t)DD : 0);
        float s_n  = S[sin];
        float sd_n = sumdelta[din];
        S[si] = carry;                       // state entering chunk c
        carry = EXP2F(A2*sd)*carry + s;      // state after chunk c
        s = s_n; sd = sd_n;
        si = sin; di = din;
    }
}

// ---------------------------------------------------------------------------
// K5 (pass 3): replay each chunk from its true incoming state, emit y.
// grid 1024 x 256. FULL 1-ahead pipeline: delta, x, AND the 8 xp float4s.
// ---------------------------------------------------------------------------
__global__ __launch_bounds__(256) void k_scan3(const float* __restrict__ x,
                                               const float* __restrict__ delta,
                                               const float* __restrict__ xp,
                                               const float* __restrict__ A_log,
                                               const float* __restrict__ Dv,
                                               const float* __restrict__ S,
                                               float* __restrict__ y) {
    const int bid = blockIdx.x;
    const int dq = bid & 7;
    const int c  = (bid >> 3) & (NC-1);
    const int b  = bid >> 9;
    const int d  = dq*256 + threadIdx.x;

    float A2[NS];
    {
        const float4* Ar = (const float4*)&A_log[(size_t)d*NS];
        #pragma unroll
        for (int q = 0; q < 4; ++q) {
            float4 v = Ar[q];
            A2[q*4+0] = -__expf(v.x) * LOG2E;
            A2[q*4+1] = -__expf(v.y) * LOG2E;
            A2[q*4+2] = -__expf(v.z) * LOG2E;
            A2[q*4+3] = -__expf(v.w) * LOG2E;
        }
    }
    float h[NS];
    size_t so = ((size_t)(b*NC + c)*NS)*DD + d;
    #pragma unroll
    for (int n = 0; n < NS; ++n) h[n] = S[so + (size_t)n*DD];
    const float Dd = Dv[d];

    const int t0 = c * CT;
    size_t base = ((size_t)b*LL + t0)*DD + d;
    const float* xpb = &xp[((size_t)b*LL + t0)*NP + RK];

    float dlt = delta[base];
    float xv  = x[base];
    float4 pv[8];
    #pragma unroll
    for (int q = 0; q < 8; ++q) pv[q] = *(const float4*)&xpb[q*4];

    for (int tt = 0; tt < CT; ++tt) {
        const int ok = (tt+1 < CT);
        const size_t nb = base + (ok ? DD : 0);
        const float* xpn = xpb + (ok ? NP : 0);
        float dlt_n = delta[nb];
        float xv_n  = x[nb];
        float4 pn[8];
        #pragma unroll
        for (int q = 0; q < 8; ++q) pn[q] = *(const float4*)&xpn[q*4];

        const float* bp = (const float*)&pv[0];
        const float* cp = (const float*)&pv[4];
        float dx = dlt * xv;
        float yt = 0.f;
        #pragma unroll
        for (int n = 0; n < NS; ++n) {
            h[n] = EXP2F(A2[n]*dlt)*h[n] + dx*bp[n];
            yt += h[n]*cp[n];
        }
        y[base] = yt + xv*Dd;

        dlt = dlt_n; xv = xv_n;
        #pragma unroll
        for (int q = 0; q < 8; ++q) pv[q] = pn[q];
        base += DD; xpb += NP;
    }
}

// ---------------------------------------------------------------------------
extern "C" void kernel_launch(void* const* d_in, const int* in_sizes, int n_in,
                              void* d_out, int out_size, void* d_ws, size_t ws_size,
                              hipStream_t stream) {
    const float* x     = (const float*)d_in[0];
    const float* A_log = (const float*)d_in[1];
    const float* Dv    = (const float*)d_in[2];
    const float* Wx    = (const float*)d_in[3];
    const float* Wdt   = (const float*)d_in[4];
    const float* bdt   = (const float*)d_in[5];
    float* y = (float*)d_out;

    // ws layout (floats): xp[4096*96] | delta[4096*2048] | S[2*64*16*2048] | sumdelta[2*64*2048]
    // proj1 partials (4*4096*96 floats) alias the delta region; delta itself is
    // written (by proj2) only after k_reduce has consumed them.  ~53 MB total.
    float* ws    = (float*)d_ws;
    float* xp    = ws;
    float* delta = xp + (size_t)4096*NP;
    float* S     = delta + (size_t)4096*DD;
    float* sumd  = S + (size_t)BB*NC*NS*DD;
    float* part  = delta;

    k_proj1<<<dim3(64, P1_KS), 256, 0, stream>>>(x, Wx, part);
    k_reduce<<<384, 256, 0, stream>>>(part, xp);
    k_proj2<<<dim3(32, 16), 256, 0, stream>>>(xp, Wdt, bdt, delta);
    k_scan1<<<1024, 256, 0, stream>>>(x, delta, xp, A_log, S, sumd);
    k_scan2<<<256, 256, 0, stream>>>(A_log, sumd, S);
    k_scan3<<<1024, 256, 0, stream>>>(x, delta, xp, A_log, Dv, S, y);
}